// Round 8
// baseline (1152.529 us; speedup 1.0000x reference)
//
#include <hip/hip_runtime.h>
#include <hip/hip_bf16.h>
#include <math.h>

typedef __bf16 bf16;
typedef __bf16 bf16x4 __attribute__((ext_vector_type(4)));
typedef __bf16 bf16x8 __attribute__((ext_vector_type(8)));
typedef float f32x4 __attribute__((ext_vector_type(4)));
typedef _Float16 f16;
typedef _Float16 f16x4 __attribute__((ext_vector_type(4)));
typedef _Float16 f16x8 __attribute__((ext_vector_type(8)));

#define BB 64
#define NN 49
#define CENC 2048
#define SS 26
#define NSTEP 25
#define VV 10000
#define EE 512
#define HH 512
#define AAT 512
#define ALPHA_OFF (BB*NSTEP*VV)
#define NCONS 128

// T16 swizzled layout for MFMA operands: matrix M[R x K] (R%16==0, K%32==0)
// element (r,k) at sw[((rt*KC + kc)*64 + lane)*8 + j]
//   rt=r/16, kc=k/32, lane=((k%32)/8)*16 + (r%16), j=k%8, KC=K/32

struct Wks {
  unsigned int pairflag[BB][2][32]; // per-pair flags, each in own 128B line
  f16  att1_16[BB*NN*AAT];          // fp16 row-major [3136][512], benc folded
  float c0[BB*HH];                  // initial cell state
  f16  h16x[BB*HH];                 // h state row-major [64][512]; pair-exchanged via LLC
  float embg[NSTEP*BB*4*HH];        // xemb @ Wih_e^T + bih + bhh  [1600][2048]
  union {                           // fg16 live k_enc..k_steps; w.* before/after
    f16 fg16[BB*NN*4*HH];           // feat @ Wih_c^T  [3136][2048] fp16
    struct {
      bf16 Wfcn_hi[10048*HH];       // T16 (R=10000 pad 10048,K=512) — after loop
      bf16 Winh_hi[HH*CENC];        // T16 (R=512,K=2048) — dead after k_init
      bf16 Winc_hi[HH*CENC];
    } w;
  } u;
  f16  Wcomb16[2560*HH];            // fp16 T16 (R=2560,K=512): rows 0..2047 Whh, 2048.. Wdec
  bf16 mean_hi[BB*CENC];            // T16 (R=64,K=2048)
  bf16 mean_lo[BB*CENC];
  bf16 xemb_hi[NSTEP*BB*EE];        // T16 (R=1600,K=512), row=s*64+b
  bf16 xemb_lo[NSTEP*BB*EE];
  bf16 hist_hi[NSTEP*BB*HH];        // T16 (R=1600,K=512), row=s*64+b
  bf16 hist_lo[NSTEP*BB*HH];
  bf16 Wih_hi[4*HH*(EE+CENC)];      // T16 (R=2048,K=2560,KC=80)
  bf16 Wih_lo[4*HH*(EE+CENC)];
  bf16 Wenc_hi[AAT*CENC];           // T16 (R=512,K=2048,KC=64)
};

__device__ inline bf16x8 ldb8(const bf16* p){ return *(const bf16x8*)p; }
__device__ inline f32x4 mfma16(bf16x8 a, bf16x8 b, f32x4 c){
  return __builtin_amdgcn_mfma_f32_16x16x32_bf16(a, b, c, 0, 0, 0);
}
__device__ inline f32x4 mfma16f(f16x8 a, f16x8 b, f32x4 c){
  return __builtin_amdgcn_mfma_f32_16x16x32_f16(a, b, c, 0, 0, 0);
}
__device__ inline float sigm(float x){ return 1.0f/(1.0f+expf(-x)); }

__device__ inline void split8(const float* p, bf16x8& hi, bf16x8& lo){
  float4 v0 = *(const float4*)p;
  float4 v1 = *(const float4*)(p+4);
  float v[8] = {v0.x,v0.y,v0.z,v0.w,v1.x,v1.y,v1.z,v1.w};
  #pragma unroll
  for (int j=0;j<8;j++){ bf16 h=(bf16)v[j]; hi[j]=h; lo[j]=(bf16)(v[j]-(float)h); }
}

// direct-to-LDS 16B per lane
__device__ inline void gll16(const bf16* g, bf16* l){
  __builtin_amdgcn_global_load_lds(
      (const __attribute__((address_space(1))) void*)g,
      (__attribute__((address_space(3))) void*)l, 16, 0, 0);
}

// ---------------- fp32 row-major -> T16 swizzle bf16 (hi + optional lo) ------------
__global__ __launch_bounds__(256) void k_cvt_sw(const float* __restrict__ src,
    bf16* __restrict__ hi, bf16* __restrict__ lo, int R, int K, int ntile){
  int g = blockIdx.x*256 + threadIdx.x;
  if (g >= ntile*64) return;
  int tile = g>>6, lane = g&63;
  int KC = K>>5;
  int rt = tile/KC, kc = tile - rt*KC;
  int r = rt*16 + (lane&15);
  if (r >= R) r = R-1;
  int k = kc*32 + (lane>>4)*8;
  bf16x8 hv, lv;
  split8(src + (size_t)r*K + k, hv, lv);
  *(bf16x8*)(hi + (size_t)g*8) = hv;
  if (lo) *(bf16x8*)(lo + (size_t)g*8) = lv;
}

// ---------------- fp32 row-major -> T16 swizzle fp16 -------------------------------
__global__ __launch_bounds__(256) void k_cvt_sw16(const float* __restrict__ src,
    f16* __restrict__ dst, int R, int K, int ntile){
  int g = blockIdx.x*256 + threadIdx.x;
  if (g >= ntile*64) return;
  int tile = g>>6, lane = g&63;
  int KC = K>>5;
  int rt = tile/KC, kc = tile - rt*KC;
  int r = rt*16 + (lane&15);
  if (r >= R) r = R-1;
  int k = kc*32 + (lane>>4)*8;
  float4 v0 = *(const float4*)(src + (size_t)r*K + k);
  float4 v1 = *(const float4*)(src + (size_t)r*K + k + 4);
  float v[8] = {v0.x,v0.y,v0.z,v0.w,v1.x,v1.y,v1.z,v1.w};
  f16x8 hv;
  #pragma unroll
  for (int j=0;j<8;j++) hv[j] = (f16)v[j];
  *(f16x8*)(dst + (size_t)g*8) = hv;
}

// ---------------- gather caption embeddings -> T16 hi/lo ---------------------------
__global__ __launch_bounds__(256) void k_emb(const int* __restrict__ caps,
    const float* __restrict__ emb, Wks* __restrict__ ws){
  int g = blockIdx.x*256 + threadIdx.x;
  if (g >= 1600*64) return;
  int tile = g>>6, lane = g&63;
  int rt = tile>>4, kc = tile&15;
  int r = rt*16 + (lane&15);
  int s = r>>6, b = r&63;
  int k = kc*32 + (lane>>4)*8;
  int cap = caps[b*SS + s];
  bf16x8 hv, lv;
  split8(emb + (size_t)cap*EE + k, hv, lv);
  *(bf16x8*)(ws->xemb_hi + (size_t)g*8) = hv;
  *(bf16x8*)(ws->xemb_lo + (size_t)g*8) = lv;
}

// ---------------- mean over N=49 pixels -> T16 hi/lo -------------------------------
__global__ __launch_bounds__(256) void k_mean(const float* __restrict__ feat, Wks* __restrict__ ws){
  int idx = blockIdx.x*256 + threadIdx.x;
  int b = idx >> 11, ch = idx & 2047;
  const float* p = feat + (size_t)b*NN*CENC + ch;
  float s = 0.f;
  #pragma unroll
  for (int n=0;n<NN;n++) s += p[n*CENC];
  s *= (1.0f/49.0f);
  bf16 hi = (bf16)s;
  int off = (((b>>4)*64 + (ch>>5))*64 + ((ch&31)>>3)*16 + (b&15))*8 + (ch&7);
  ws->mean_hi[off] = hi;
  ws->mean_lo[off] = (bf16)(s - (float)hi);
}

// ---------------- h0/c0 init; zero pair flags --------------------------------------
__global__ __launch_bounds__(256) void k_init(Wks* __restrict__ ws,
    const float* __restrict__ bh, const float* __restrict__ bc){
  if (blockIdx.x == 0 && threadIdx.x < 128)
    ws->pairflag[threadIdx.x>>1][threadIdx.x&1][0] = 0u;
  int wid = threadIdx.x >> 6, lane = threadIdx.x & 63;
  int w = blockIdx.x*4 + wid;                // 0..63
  int mat = w >> 5, nt = w & 31;
  int lane15 = lane & 15, quad = lane >> 4;
  const bf16* Wm = mat ? ws->u.w.Winc_hi : ws->u.w.Winh_hi;
  const float* bm = mat ? bc : bh;
  int col = nt*16 + lane15;
  f32x4 acc[4] = {};
  for (int kc=0; kc<64; kc++){
    bf16x8 bfr = ldb8(Wm + (((size_t)nt*64 + kc)*64 + lane)*8);
    #pragma unroll
    for (int t=0;t<4;t++){
      acc[t] = mfma16(ldb8(ws->mean_hi + (((size_t)t*64 + kc)*64 + lane)*8), bfr, acc[t]);
      acc[t] = mfma16(ldb8(ws->mean_lo + (((size_t)t*64 + kc)*64 + lane)*8), bfr, acc[t]);
    }
  }
  float bias = bm[col];
  #pragma unroll
  for (int t=0;t<4;t++){
    #pragma unroll
    for (int r=0;r<4;r++){
      int b = t*16 + quad*4 + r;
      float v = acc[t][r] + bias;
      if (mat == 0) ws->h16x[(size_t)b*HH + col] = (f16)v;
      else          ws->c0[b*HH + col] = v;
    }
  }
}

// ---------------- embgates = xemb @ Wih_e^T + bih + bhh  [1600][2048] --------------
__global__ __launch_bounds__(256) void k_embg(Wks* __restrict__ ws,
    const float* __restrict__ bih, const float* __restrict__ bhh){
  int wid = threadIdx.x>>6, lane = threadIdx.x&63;
  int w = blockIdx.x*4 + wid;                // 3200 waves: w = nt*25 + mtg
  int nt = w/25, mtg = w - nt*25;
  int lane15 = lane&15, quad = lane>>4;
  f32x4 acc[4] = {};
  for (int kc=0; kc<16; kc++){
    bf16x8 wh = ldb8(ws->Wih_hi + (((size_t)nt*80 + kc)*64 + lane)*8);
    bf16x8 wl = ldb8(ws->Wih_lo + (((size_t)nt*80 + kc)*64 + lane)*8);
    #pragma unroll
    for (int i=0;i<4;i++){
      int rt = mtg*4 + i;
      bf16x8 ah = ldb8(ws->xemb_hi + (((size_t)rt*16 + kc)*64 + lane)*8);
      bf16x8 al = ldb8(ws->xemb_lo + (((size_t)rt*16 + kc)*64 + lane)*8);
      acc[i] = mfma16(ah, wh, acc[i]);
      acc[i] = mfma16(al, wh, acc[i]);
      acc[i] = mfma16(ah, wl, acc[i]);
    }
  }
  int col = nt*16 + lane15;
  float bias = bih[col] + bhh[col];
  #pragma unroll
  for (int i=0;i<4;i++){
    #pragma unroll
    for (int r=0;r<4;r++){
      int row = (mtg*4+i)*16 + quad*4 + r;   // row = s*64 + b
      ws->embg[(size_t)row*(4*HH) + col] = acc[i][r] + bias;
    }
  }
}

// ---------------- encoder GEMM: att1(f16) + featgates(f16) in one pass over feat ---
__global__ __launch_bounds__(256) void k_enc(const float* __restrict__ feat,
    const float* __restrict__ benc, Wks* __restrict__ ws)
{
  __shared__ bf16 sm[2][24*512];
  // bijective XCD swizzle over 980 wgs (q=122, r=4), mb-major within XCD chunk
  int xcd = blockIdx.x & 7, idx = blockIdx.x >> 3;
  int wg = (xcd < 4) ? xcd*123 + idx : 4*123 + (xcd-4)*122 + idx;
  int mb = wg / 20, nb = wg % 20;
  int tid = threadIdx.x, wid = tid>>6, lane = tid&63;
  int lane15 = lane&15, quad = lane>>4;
  bool is_fg = (nb < 16);
  int rr = tid>>2, qo = tid&3;
  const float* arow = feat + (size_t)(mb*64 + rr)*CENC + qo*8;
  int a_ds = ((rr>>4)*2)*512 + (qo*16 + (rr&15))*8;

  f32x4 acc[8] = {};

  auto stageB = [&](int kc, int buf){
    if (is_fg){
      #pragma unroll
      for (int j=0;j<4;j++){
        int tt = wid*4 + j;
        int ntl = tt>>1;
        const bf16* src = ((tt&1) ? ws->Wih_lo : ws->Wih_hi)
            + (size_t)((nb*8 + ntl)*80 + 16 + kc)*512 + lane*8;
        gll16(src, &sm[buf][(8+tt)*512]);
      }
    } else {
      #pragma unroll
      for (int j=0;j<2;j++){
        int tt = wid*2 + j;
        const bf16* src = ws->Wenc_hi
            + (size_t)(((nb-16)*8 + tt)*64 + kc)*512 + lane*8;
        gll16(src, &sm[buf][(8+tt)*512]);
      }
    }
  };
  auto cvtwr = [&](int buf, float4 v0, float4 v1){
    float v[8] = {v0.x,v0.y,v0.z,v0.w,v1.x,v1.y,v1.z,v1.w};
    bf16x8 hv, lv;
    #pragma unroll
    for (int j=0;j<8;j++){ bf16 h=(bf16)v[j]; hv[j]=h; lv[j]=(bf16)(v[j]-(float)h); }
    *(bf16x8*)(&sm[buf][a_ds]) = hv;
    *(bf16x8*)(&sm[buf][a_ds+512]) = lv;
  };

  stageB(0, 0);
  { float4 v0 = *(const float4*)arow;
    float4 v1 = *(const float4*)(arow+4);
    cvtwr(0, v0, v1); }
  __syncthreads();

  for (int kc=0; kc<64; kc++){
    int cur = kc & 1;
    bool pf = (kc < 63);
    float4 v0, v1;
    if (pf){
      stageB(kc+1, cur^1);
      const float* p = arow + (kc+1)*32;
      v0 = *(const float4*)p; v1 = *(const float4*)(p+4);
    }
    const bf16* S = sm[cur];
    bf16x8 ah = ldb8(S + (wid*2)*512 + lane*8);
    bf16x8 al = ldb8(S + (wid*2+1)*512 + lane*8);
    if (is_fg){
      #pragma unroll
      for (int u=0;u<8;u++){
        bf16x8 wh = ldb8(S + (size_t)(8+u*2)*512 + lane*8);
        bf16x8 wl = ldb8(S + (size_t)(9+u*2)*512 + lane*8);
        acc[u] = mfma16(ah, wh, acc[u]);
        acc[u] = mfma16(al, wh, acc[u]);
        acc[u] = mfma16(ah, wl, acc[u]);
      }
    } else {
      #pragma unroll
      for (int u=0;u<8;u++){
        bf16x8 wh = ldb8(S + (size_t)(8+u)*512 + lane*8);
        acc[u] = mfma16(ah, wh, acc[u]);
        acc[u] = mfma16(al, wh, acc[u]);
      }
    }
    if (pf) cvtwr(cur^1, v0, v1);
    __syncthreads();
  }

  if (is_fg){
    #pragma unroll
    for (int u=0;u<8;u++){
      int col = nb*128 + u*16 + lane15;
      #pragma unroll
      for (int r=0;r<4;r++){
        int row = mb*64 + wid*16 + quad*4 + r;
        ws->u.fg16[(size_t)row*(4*HH) + col] = (f16)acc[u][r];
      }
    }
  } else {
    #pragma unroll
    for (int u=0;u<8;u++){
      int col = (nb-16)*128 + u*16 + lane15;
      float bias = benc[col];
      #pragma unroll
      for (int r=0;r<4;r++){
        int row = mb*64 + wid*16 + quad*4 + r;
        ws->att1_16[(size_t)row*AAT + col] = (f16)(acc[u][r] + bias);
      }
    }
  }
}

// ---------------- step loop: fully block-local, pairwise h exchange only -----------
// grid = 128 x 256, block (b,jh). fg half + att1 pinned in LDS. Per step each block
// computes its OWN att2[512] + hwhh[its 1024 gate-cols] via broadcast-A MFMA over
// L2-cached Wcomb16 (T16). Only cross-block traffic: 512B h-half pair exchange via
// LLC (sc0 sc1) + per-pair flag in its own cache line (1 poller — no contention).
__global__ __launch_bounds__(256) void k_steps(Wks* __restrict__ ws,
    const float* __restrict__ bdec, const float* __restrict__ Wfull,
    float* __restrict__ out)
{
  __shared__ __align__(16) unsigned char smem[162304];
  f16*   att1_s = (f16*)smem;                  // 50176 B
  f16*   fg_s   = (f16*)(smem + 50176);        // 100352 B, [n][g][256]
  f16*   h_s    = (f16*)(smem + 150528);       // 1024 B: full h[b]
  float* hw_s   = (float*)(smem + 151552);     // 6144 B: [0..1023] gates, [1024..1535] att2
  float* wf_s   = (float*)(smem + 157696);     // 2048 B
  float* bd_s   = (float*)(smem + 159744);     // 2048 B
  float* e_s    = (float*)(smem + 161792);     // 256 B
  float* al_s   = (float*)(smem + 162048);     // 256 B
  int blk = blockIdx.x, tid = threadIdx.x;
  int lane = tid & 63, wid = tid >> 6, quad = lane >> 4;
  int b = blk >> 1, jh = blk & 1;

  for (int i = tid; i < NN*64; i += 256)
    *(f16x8*)(att1_s + (size_t)i*8) =
        *(const f16x8*)(ws->att1_16 + ((size_t)b*NN*64 + i)*8);
  for (int i = tid; i < NN*4*32; i += 256){
    int n = i >> 7, rem = i & 127, g2 = rem >> 5, c8 = rem & 31;
    *(f16x8*)(fg_s + (((n<<2) + g2)<<8) + c8*8) =
        *(const f16x8*)(ws->u.fg16 + (size_t)(b*NN+n)*2048 + g2*512 + jh*256 + c8*8);
  }
  wf_s[tid] = Wfull[tid]; wf_s[tid+256] = Wfull[tid+256];
  bd_s[tid] = bdec[tid];  bd_s[tid+256] = bdec[tid+256];
  if (tid < 64)
    *(f16x8*)(h_s + tid*8) = *(const f16x8*)(ws->h16x + (size_t)b*HH + tid*8);
  float c_reg = ws->c0[b*HH + jh*256 + tid];
  int g = tid>>6, i4 = (tid&63)*4;
  int gc = g*512 + jh*256 + i4;
  int col = jh*256 + tid;
  int kcc = col>>5, lane_w = ((col&31)>>3)*16 + (b&15), j8 = col&7;
  __syncthreads();

  for (int t=0; t<NSTEP; t++){
    // embg prefetch (hides under matvec)
    float4 ev = *(const float4*)(ws->embg + (size_t)(t*64+b)*2048 + gc);
    // ---- A-fragments: h broadcast to all 16 rows (every row computes same dot) ----
    f16x8 af[16];
    #pragma unroll
    for (int k2=0;k2<16;k2++)
      af[k2] = *(const f16x8*)(h_s + k2*32 + quad*8);
    // ---- matvec: wave handles 24 of 96 tiles, 4 independent acc chains ----
    for (int g4=0; g4<6; g4++){
      int wt[4], dst[4];
      #pragma unroll
      for (int u=0;u<4;u++){
        int tt = wid*24 + g4*4 + u;
        if (tt < 64){ int gg=tt>>4, uu=tt&15; wt[u]=gg*32+jh*16+uu; dst[u]=gg*256+uu*16; }
        else        { wt[u]=128+(tt-64); dst[u]=1024+(tt-64)*16; }
      }
      f32x4 a0={}, a1={}, a2={}, a3={};
      #pragma unroll
      for (int k2=0;k2<16;k2++){
        const f16* base = ws->Wcomb16 + (size_t)k2*512 + (size_t)lane*8;
        f16x8 b0 = *(const f16x8*)(base + (size_t)wt[0]*8192);
        f16x8 b1 = *(const f16x8*)(base + (size_t)wt[1]*8192);
        f16x8 b2 = *(const f16x8*)(base + (size_t)wt[2]*8192);
        f16x8 b3 = *(const f16x8*)(base + (size_t)wt[3]*8192);
        a0 = mfma16f(af[k2], b0, a0);
        a1 = mfma16f(af[k2], b1, a1);
        a2 = mfma16f(af[k2], b2, a2);
        a3 = mfma16f(af[k2], b3, a3);
      }
      if (lane < 16){
        float v0 = a0[0], v1 = a1[0], v2 = a2[0], v3 = a3[0];
        if (dst[0] >= 1024){
          v0 += bd_s[dst[0]-1024+lane];
          v1 += bd_s[dst[1]-1024+lane];
          v2 += bd_s[dst[2]-1024+lane];
          v3 += bd_s[dst[3]-1024+lane];
        }
        hw_s[dst[0]+lane] = v0;
        hw_s[dst[1]+lane] = v1;
        hw_s[dst[2]+lane] = v2;
        hw_s[dst[3]+lane] = v3;
      }
    }
    __syncthreads();
    float4 gacc;
    {
      float4 hv4 = *(const float4*)(hw_s + g*256 + i4);
      gacc.x = ev.x + hv4.x;
      gacc.y = ev.y + hv4.y;
      gacc.z = ev.z + hv4.z;
      gacc.w = ev.w + hv4.w;
    }
    // ---- e[n] = relu(att1 + att2) . wf ----
    for (int n = wid; n < NN; n += 4){
      f16x8 a1v = *(const f16x8*)(att1_s + n*512 + lane*8);
      float s = 0.f;
      #pragma unroll
      for (int j=0;j<8;j++){
        float v = (float)a1v[j] + hw_s[1024 + lane*8 + j];
        v = fmaxf(v, 0.f);
        s += v * wf_s[lane*8+j];
      }
      #pragma unroll
      for (int off=32; off; off>>=1) s += __shfl_xor(s, off, 64);
      if (lane==0) e_s[n] = s;
    }
    __syncthreads();
    if (wid==0){
      float e = (lane < NN) ? e_s[lane] : -1e30f;
      float m = e;
      #pragma unroll
      for (int off=32; off; off>>=1) m = fmaxf(m, __shfl_xor(m, off, 64));
      float p = (lane < NN) ? expf(e - m) : 0.f;
      float su = p;
      #pragma unroll
      for (int off=32; off; off>>=1) su += __shfl_xor(su, off, 64);
      float al = p/su;
      if (lane < NN){
        al_s[lane] = al;
        if (jh==0) out[ALPHA_OFF + (size_t)(b*NSTEP + t)*NN + lane] = al;
      }
    }
    __syncthreads();
    // ---- gate-sum from LDS-resident fg; write back into hw_s (same slots) ----
    {
      const f16* fp_ = fg_s + (g<<8) + i4;
      #pragma unroll 7
      for (int n=0;n<NN;n++){
        float a = al_s[n];
        f16x4 v = *(const f16x4*)(fp_ + (size_t)n*1024);
        gacc.x += a*(float)v[0];
        gacc.y += a*(float)v[1];
        gacc.z += a*(float)v[2];
        gacc.w += a*(float)v[3];
      }
      *(float4*)(hw_s + (g<<8) + i4) = gacc;
    }
    __syncthreads();
    // ---- LSTM pointwise: thread owns h-col = jh*256+tid ----
    {
      float iv = hw_s[tid], fv = hw_s[256+tid], gv = hw_s[512+tid], ov = hw_s[768+tid];
      float cn = sigm(fv)*c_reg + sigm(iv)*tanhf(gv);
      float hn = sigm(ov)*tanhf(cn);
      c_reg = cn;
      h_s[col] = (f16)hn;
      bf16 hi_ = (bf16)hn;
      bf16 lo_ = (bf16)(hn - (float)hi_);
      size_t offhist = ((((size_t)t*4 + (b>>4))*16 + kcc)*64 + lane_w)*8 + j8;
      ws->hist_hi[offhist] = hi_;
      ws->hist_lo[offhist] = lo_;
    }
    __syncthreads();
    if (t < NSTEP-1){
      // ---- pairwise h exchange via LLC (ext-vector types for asm operands) ----
      if (tid < 32){
        f32x4 hv = *(const f32x4*)((const char*)h_s + jh*512 + tid*16);
        asm volatile("global_store_dwordx4 %0, %1, off sc0 sc1"
            :: "v"((char*)ws->h16x + (size_t)b*1024 + jh*512 + tid*16), "v"(hv)
            : "memory");
        asm volatile("s_waitcnt vmcnt(0)" ::: "memory");
      }
      __syncthreads();
      if (tid == 0){
        unsigned fl = (unsigned)(t+1);
        asm volatile("global_store_dword %0, %1, off sc0 sc1"
            :: "v"(&ws->pairflag[b][jh][0]), "v"(fl) : "memory");
        unsigned got = 0;
        do {
          __builtin_amdgcn_s_sleep(1);
          asm volatile("global_load_dword %0, %1, off sc0 sc1"
              : "=v"(got) : "v"(&ws->pairflag[b][jh^1][0]));
          asm volatile("s_waitcnt vmcnt(0)" ::: "memory");
        } while (got <= (unsigned)t);
      }
      __syncthreads();
      if (tid < 32){
        f32x4 hv;
        asm volatile("global_load_dwordx4 %0, %1, off sc0 sc1"
            : "=v"(hv)
            : "v"((const char*)ws->h16x + (size_t)b*1024 + (jh^1)*512 + tid*16));
        asm volatile("s_waitcnt vmcnt(0)" ::: "memory");
        __builtin_amdgcn_sched_barrier(0);
        *(f32x4*)((char*)h_s + (jh^1)*512 + tid*16) = hv;
      }
      __syncthreads();
    }
  }
}

// ---------------- final pred GEMM: [1600 x 10000] = hist @ Wfcn^T (T16) ------------
__global__ __launch_bounds__(256) void k_pred(Wks* __restrict__ ws,
    const float* __restrict__ bfcn, float* __restrict__ out)
{
  int wid = threadIdx.x>>6, lane = threadIdx.x&63;
  int mt = blockIdx.y*4 + wid;
  int nt = blockIdx.x;
  if (mt >= NSTEP) return;
  int lane15 = lane&15, quad = lane>>4;
  int n0 = nt*64;
  f32x4 acc[4][4] = {};
  for (int kc=0; kc<16; kc++){
    bf16x8 a_hi[4], a_lo[4], bw[4];
    #pragma unroll
    for (int i=0;i<4;i++){
      a_hi[i] = ldb8(ws->hist_hi + (((size_t)(mt*4+i)*16 + kc)*64 + lane)*8);
      a_lo[i] = ldb8(ws->hist_lo + (((size_t)(mt*4+i)*16 + kc)*64 + lane)*8);
    }
    #pragma unroll
    for (int u=0;u<4;u++)
      bw[u] = ldb8(ws->u.w.Wfcn_hi + (((size_t)(nt*4+u)*16 + kc)*64 + lane)*8);
    #pragma unroll
    for (int u=0;u<4;u++){
      #pragma unroll
      for (int i=0;i<4;i++){
        acc[u][i] = mfma16(a_hi[i], bw[u], acc[u][i]);
        acc[u][i] = mfma16(a_lo[i], bw[u], acc[u][i]);
      }
    }
  }
  #pragma unroll
  for (int u=0;u<4;u++){
    int vc = n0 + u*16 + lane15;
    if (vc < VV){
      float bias = bfcn[vc];
      #pragma unroll
      for (int i=0;i<4;i++){
        #pragma unroll
        for (int r=0;r<4;r++){
          int row = mt*64 + i*16 + quad*4 + r;   // row = s*64 + b
          int sstep = row >> 6, bidx = row & 63;
          out[(size_t)(bidx*NSTEP + sstep)*VV + vc] = acc[u][i][r] + bias;
        }
      }
    }
  }
}

extern "C" void kernel_launch(void* const* d_in, const int* in_sizes, int n_in,
                              void* d_out, int out_size, void* d_ws, size_t ws_size,
                              hipStream_t stream)
{
  const float* feat = (const float*)d_in[0];
  const int*   caps = (const int*)d_in[1];
  const float* emb  = (const float*)d_in[2];
  const float* Wih  = (const float*)d_in[3];
  const float* bih  = (const float*)d_in[4];
  const float* Whh  = (const float*)d_in[5];
  const float* bhh  = (const float*)d_in[6];
  const float* Wenc = (const float*)d_in[7];
  const float* benc = (const float*)d_in[8];
  const float* Wdec = (const float*)d_in[9];
  const float* bdec = (const float*)d_in[10];
  const float* Wfull= (const float*)d_in[11];
  const float* bfull= (const float*)d_in[12];
  const float* Winh = (const float*)d_in[13];
  const float* binh = (const float*)d_in[14];
  const float* Winc = (const float*)d_in[15];
  const float* binc = (const float*)d_in[16];
  const float* Wfcn = (const float*)d_in[17];
  const float* bfcn = (const float*)d_in[18];
  float* out = (float*)d_out;
  Wks* ws = (Wks*)d_ws;
  if (ws_size < sizeof(Wks)) return;
  (void)bfull;

  #define SW(src, hi, lo, R, K) do { int nt_ = ((R+15)/16)*((K)/32); \
    hipLaunchKernelGGL(k_cvt_sw, dim3((nt_*64+255)/256), dim3(256), 0, stream, \
        src, hi, lo, R, K, nt_); } while(0)
  SW(Wih,  ws->Wih_hi,  ws->Wih_lo,  2048, 2560);
  SW(Wenc, ws->Wenc_hi, (bf16*)nullptr, 512, 2048);
  SW(Winh, ws->u.w.Winh_hi, (bf16*)nullptr, 512, 2048);
  SW(Winc, ws->u.w.Winc_hi, (bf16*)nullptr, 512, 2048);
  // Wcomb16 fp16 T16: rows 0..2047 = Whh, rows 2048..2559 = Wdec
  hipLaunchKernelGGL(k_cvt_sw16, dim3((128*16*64+255)/256), dim3(256), 0, stream,
      Whh, ws->Wcomb16, 2048, 512, 128*16);
  hipLaunchKernelGGL(k_cvt_sw16, dim3((32*16*64+255)/256), dim3(256), 0, stream,
      Wdec, ws->Wcomb16 + (size_t)2048*512, 512, 512, 32*16);
  hipLaunchKernelGGL(k_emb, dim3(400), dim3(256), 0, stream, caps, emb, ws);
  hipLaunchKernelGGL(k_mean, dim3(512), dim3(256), 0, stream, feat, ws);
  hipLaunchKernelGGL(k_init, dim3(16), dim3(256), 0, stream, ws, binh, binc);
  hipLaunchKernelGGL(k_embg, dim3(800), dim3(256), 0, stream, ws, bih, bhh);
  hipLaunchKernelGGL(k_enc, dim3(980), dim3(256), 0, stream, feat, benc, ws);
  hipLaunchKernelGGL(k_steps, dim3(NCONS), dim3(256), 0, stream,
      ws, bdec, Wfull, out);
  // fg16 dead now: reuse its space for the Wfcn swizzle, then pred
  SW(Wfcn, ws->u.w.Wfcn_hi, (bf16*)nullptr, 10000, 512);
  #undef SW
  hipLaunchKernelGGL(k_pred, dim3(157, 7), dim3(256), 0, stream, ws, bfcn, out);
}